// Round 5
// baseline (1515.417 us; speedup 1.0000x reference)
//
#include <hip/hip_runtime.h>
#include <hip/hip_bf16.h>
#include <math.h>

// ---- problem constants ----
#define BB     16
#define HH     64
#define WWID   64
#define CCH    512
#define HEADS  16
#define NTOK   64
#define DDIM   32
#define NWIN   64
#define LL     (HH*WWID)       // 4096
#define MTOT   (BB*LL)         // 65536 rows
#define BWIN   (BB*NWIN)       // 1024 windows
#define HIDN   2048
#define SHIFT_ 4

typedef unsigned short u16;
using bf16x8 = __attribute__((ext_vector_type(8))) short;   // 8 bf16 (4 VGPRs)
using f32x4  = __attribute__((ext_vector_type(4))) float;
using f32x16 = __attribute__((ext_vector_type(16))) float;

__device__ __forceinline__ u16 f2bf(float f) {
  union { float f; unsigned u; } v; v.f = f;
  unsigned r = v.u + 0x7fffu + ((v.u >> 16) & 1u);   // RNE
  return (u16)(r >> 16);
}
__device__ __forceinline__ float bf2f(unsigned h) {
  union { unsigned u; float f; } v; v.u = h << 16;
  return v.f;
}
// packed f32x2 -> bf16x2 (hardware RNE, 1 instr for 2 elems)
__device__ __forceinline__ unsigned cvtpk(float lo, float hi) {
  unsigned r;
  asm("v_cvt_pk_bf16_f32 %0, %1, %2" : "=v"(r) : "v"(lo), "v"(hi));
  return r;
}
// fast GELU: x*sigmoid(1.5958(x+0.044715x^3)); |err| ~1e-3 << bf16 quant noise
__device__ __forceinline__ float gelu_f(float v) {
  float v3 = v * v * v;
  float y = 1.5957691216057308f * v + 0.0713548162726009f * v3;
  return v / (1.f + __expf(-y));
}

__device__ __forceinline__ void gload16(const void* g, void* l) {
  __builtin_amdgcn_global_load_lds((const __attribute__((address_space(1))) void*)g,
                                   (__attribute__((address_space(3))) void*)l, 16, 0, 0);
}

// shifted-window mapping: windowed token (b_, n) -> original row index in x
__device__ __forceinline__ int win2orig(int b_, int n) {
  int b = b_ >> 6, wi = b_ & 63;
  int hs = (wi >> 3) * 8 + (n >> 3);
  int ws = (wi & 7) * 8 + (n & 7);
  int hq = (hs + SHIFT_) & 63;
  int wq = (ws + SHIFT_) & 63;
  return b * LL + hq * WWID + wq;
}

// ---------------- tiny setup kernels ----------------
__global__ void cvt_k(const float* __restrict__ s, u16* __restrict__ d, int n) {
  int i = blockIdx.x * 256 + threadIdx.x;
  if (i < n) d[i] = f2bf(s[i]);
}

__global__ void cpb_k(const float* __restrict__ ct, const float* __restrict__ w1,
                      const float* __restrict__ b1, const float* __restrict__ w2,
                      float* __restrict__ t2) {
  int t = blockIdx.x * 256 + threadIdx.x;
  if (t >= 225 * 16) return;
  int rr = t >> 4, h = t & 15;
  float c0 = ct[rr * 2], c1 = ct[rr * 2 + 1];
  float acc = 0.f;
  for (int j = 0; j < 512; j++) {
    float hv = fmaxf(w1[j * 2] * c0 + w1[j * 2 + 1] * c1 + b1[j], 0.f);
    acc += hv * w2[h * 512 + j];
  }
  t2[t] = acc;
}

__global__ void bias_k(const float* __restrict__ t2, const int* __restrict__ rpi,
                       float* __restrict__ b16) {
  int t = blockIdx.x * 256 + threadIdx.x;   // h*4096 + n*64 + m
  int nm = t & 4095;
  int h = t >> 12;
  float v = t2[rpi[nm] * 16 + h];
  b16[t] = 16.0f / (1.0f + __expf(-v));
}

__global__ void scale_k(const float* __restrict__ ls, float* __restrict__ sc) {
  int t = threadIdx.x;
  if (t < HEADS) sc[t] = __expf(fminf(ls[t], 4.6051701859880914f)); // ln(100)
}

// x (fp32) -> xw (bf16) in shifted-window token order [b_*64+n][512]
__global__ __launch_bounds__(256) void xw_k(const float* __restrict__ x, u16* __restrict__ xw) {
  int t = blockIdx.x * 256 + threadIdx.x;
  int row = t >> 6;
  int col = (t & 63) * 8;
  const float* src = x + (size_t)win2orig(row >> 6, row & 63) * CCH + col;
  float4 a = *(const float4*)src;
  float4 b = *(const float4*)(src + 4);
  uint4 o = make_uint4(cvtpk(a.x, a.y), cvtpk(a.z, a.w),
                       cvtpk(b.x, b.y), cvtpk(b.z, b.w));
  *(uint4*)(xw + (size_t)row * CCH + col) = o;
}

// ---------------- MFMA GEMM, 256x128 block tile, 32x32x16 MFMA ----------------
// A bf16 [M][K], B bf16 [N][K] -> C = A @ B^T.
// 8 waves (512 thr), wave grid 4M x 2N, wave tile 64x64 (acc[2][2] = 64 VGPR).
// B-operand DIRECT-TO-REGISTER from global (weights are L2-resident; per row
//   per iter the 4x16B fragment loads consume exactly one 64B line). LDS holds
//   A only: per-block-step LDS traffic 96KB -> 32KB, footprint 72 -> 48KB,
//   so 2 blocks/CU = 16 waves (VGPR<=128 via __launch_bounds__(512,4)).
// mfma(b,a): acc holds C^T; lane owns a fixed output row, regs walk N.
// Epilogue: v_permlane32_swap_b32 assembles 8 contiguous channels/lane ->
//   16B uint4 stores; khalf pair covers full 32B sectors.
// Main loop: depth-2 A pipeline, 3 LDS buffers, raw s_barrier + counted
//   s_waitcnt vmcnt(2) (2 A gload_lds per tile; never drains in steady state).
// A LDS swizzle: s(row) = (row + (row>>2)) & 3, chunk c stored at c^s(row);
//   applied on the (per-lane) global source addr, LDS dest stays linear.
// XCD swizzle: lin%8 -> XCD, contiguous M-chunk per XCD for A-tile L2 reuse.
// MODE 0: QKV (epi: +q/v bias, scatter to [b_][h][n][d] bf16)
// MODE 1: proj (epi: +proj_b, bf16 scatter to original token order)
// MODE 2: fc1  (epi: +fc1_b, fast GELU, bf16 ld=HIDN)
// MODE 3: fc2  (epi: +fc2_b, bf16 ld=CCH)
template<int MODE, int NBN>
__global__ __launch_bounds__(512, 4) void gemm256_k(
    const u16* __restrict__ A, const u16* __restrict__ Bw,
    const float* __restrict__ bias,
    const float* __restrict__ qbias, const float* __restrict__ vbias,
    u16* __restrict__ o0, u16* __restrict__ o1, u16* __restrict__ o2,
    int K, int mchunk)
{
  // 3 A-buffers: 256 rows x 32 k x 2B = 16 KB each, 48 KB total
  __shared__ __align__(16) u16 smem[3 * 8192];
  const int t = threadIdx.x;
  const int lin = blockIdx.x;
  const int xcd = lin & 7;
  const int j = lin >> 3;
  const int m0 = (xcd * mchunk + j / NBN) * 256;
  const int n0 = (j % NBN) * 128;
  const int lane = t & 63;
  const int wv = t >> 6;          // 0..7
  const int wm = (wv >> 1) * 64;  // M sub-tile (4 groups)
  const int wn = (wv & 1) * 64;   // N sub-tile (2 groups)
  const int l31 = lane & 31;
  const int khalf = lane >> 5;    // 0/1

  // A staging: chunk c = i*512 + t; row = c>>2 = i*128 + (t>>2); s(row) below.
  const int sstg = (((t >> 2) + (t >> 4)) & 3);
  const int swcol = (((t & 3) ^ sstg) * 8);
  const u16* aP[2]; int aL[2];
  #pragma unroll
  for (int i = 0; i < 2; i++) {
    aP[i] = A + (size_t)(m0 + i * 128 + (t >> 2)) * K + swcol;
    aL[i] = i * 8192 + wv * 1024;
  }
  // B fragment pointers (per-lane, global): row = n0+wn+nt*32+l31
  const u16* bReg[2];
  #pragma unroll
  for (int nt = 0; nt < 2; nt++)
    bReg[nt] = Bw + (size_t)(n0 + wn + nt * 32 + l31) * K + khalf * 8;

  f32x16 acc[2][2] = {};

  auto stage = [&](int k0, int bi) {
    char* base = (char*)smem + bi * 16384;
    #pragma unroll
    for (int i = 0; i < 2; i++) gload16(aP[i] + k0, base + aL[i]);
  };

  const int NT = K >> 5;
  stage(0, 0);
  stage(32, 1);

  // read-side swizzle: row = wm + mt*32 + l31 -> s depends only on l31
  const int srd = ((l31 & 3) + ((l31 >> 2) & 3)) & 3;

  for (int it = 0; it < NT; ++it) {
    const int k0 = it << 5;
    // own tile-it A loads complete (oldest); tile it+1 stays in flight
    if (it + 1 < NT) asm volatile("s_waitcnt vmcnt(2)" ::: "memory");
    else             asm volatile("s_waitcnt vmcnt(0)" ::: "memory");
    __builtin_amdgcn_s_barrier();       // all waves: tile it ready; reads of it-1 done
    asm volatile("" ::: "memory");      // keep ds_reads below the barrier

    // B fragments for this iter (L2-hit; latency hides under ds_reads)
    bf16x8 bf[2][2];
    #pragma unroll
    for (int nt = 0; nt < 2; nt++)
      #pragma unroll
      for (int ks = 0; ks < 2; ks++)
        bf[nt][ks] = *(const bf16x8*)(bReg[nt] + k0 + ks * 16);

    if (it + 2 < NT) stage((it + 2) << 5, (it + 2) % 3);

    const u16* Ab = (const u16*)((const char*)smem + (it % 3) * 16384);
    #pragma unroll
    for (int ks = 0; ks < 2; ks++) {
      const int kc = (ks * 2 + khalf) ^ srd;   // swizzled k-chunk (A only)
      bf16x8 af[2];
      #pragma unroll
      for (int mt = 0; mt < 2; mt++)
        af[mt] = *(const bf16x8*)&Ab[(wm + mt * 32 + l31) * 32 + kc * 8];
      #pragma unroll
      for (int mt = 0; mt < 2; mt++)
        #pragma unroll
        for (int nt = 0; nt < 2; nt++)
          acc[mt][nt] = __builtin_amdgcn_mfma_f32_32x32x16_bf16(bf[nt][ks], af[mt], acc[mt][nt], 0, 0, 0);
    }
    // next iteration's barrier protects LDS buffer reuse
  }

  // epilogue: acc holds C^T tiles.
  //   row = m0+wm+mt*32+l31 (fixed/lane); own cols = cb + 8g + 4*khalf (+0..3)
  const int part = n0 >> 9;   // MODE 0 only (tile never spans q/k/v parts)
  u16* qkvdst = (MODE == 0) ? (part == 0 ? o0 : (part == 1 ? o1 : o2)) : o0;
  #pragma unroll
  for (int mt = 0; mt < 2; mt++) {
    const int grow = m0 + wm + mt * 32 + l31;
    size_t rowbase;
    if (MODE == 0) {
      int b_ = grow >> 6, n = grow & 63;
      rowbase = ((size_t)b_ * HEADS) * (NTOK * DDIM) + (size_t)n * DDIM;
    } else if (MODE == 1) {
      rowbase = (size_t)win2orig(grow >> 6, grow & 63) * CCH;
    } else if (MODE == 2) {
      rowbase = (size_t)grow * HIDN;
    } else {
      rowbase = (size_t)grow * CCH;
    }
    #pragma unroll
    for (int nt = 0; nt < 2; nt++) {
      const int cb = n0 + wn + nt * 32;          // 32-aligned channel base
      unsigned U[4], W[4];
      #pragma unroll
      for (int g = 0; g < 4; g++) {
        const int nb = cb + 8 * g + 4 * khalf;
        float v0 = acc[mt][nt][g * 4 + 0];
        float v1 = acc[mt][nt][g * 4 + 1];
        float v2 = acc[mt][nt][g * 4 + 2];
        float v3 = acc[mt][nt][g * 4 + 3];
        if (MODE == 0) {
          const int cc = nb & 511;
          if (part == 0) {
            float4 b4 = *(const float4*)(qbias + cc);
            v0 += b4.x; v1 += b4.y; v2 += b4.z; v3 += b4.w;
          } else if (part == 2) {
            float4 b4 = *(const float4*)(vbias + cc);
            v0 += b4.x; v1 += b4.y; v2 += b4.z; v3 += b4.w;
          }
        } else {
          float4 b4 = *(const float4*)(bias + nb);
          v0 += b4.x; v1 += b4.y; v2 += b4.z; v3 += b4.w;
          if (MODE == 2) {
            v0 = gelu_f(v0); v1 = gelu_f(v1); v2 = gelu_f(v2); v3 = gelu_f(v3);
          }
        }
        U[g] = cvtpk(v0, v1);
        W[g] = cvtpk(v2, v3);
      }
      // A.high <-> B.low swaps: assemble 8 contiguous channels per lane
      asm volatile("v_permlane32_swap_b32 %0, %1" : "+v"(U[0]), "+v"(U[1]));
      asm volatile("v_permlane32_swap_b32 %0, %1" : "+v"(W[0]), "+v"(W[1]));
      asm volatile("v_permlane32_swap_b32 %0, %1" : "+v"(U[2]), "+v"(U[3]));
      asm volatile("v_permlane32_swap_b32 %0, %1" : "+v"(W[2]), "+v"(W[3]));
      uint4 s1 = make_uint4(U[0], W[0], U[1], W[1]);   // cols [cb+8k, cb+8k+8)
      uint4 s2 = make_uint4(U[2], W[2], U[3], W[3]);   // cols [cb+16+8k, +8)
      if (MODE == 0) {
        const int cc1 = (cb & 511) + 8 * khalf;
        const int cc2 = cc1 + 16;
        *(uint4*)(qkvdst + rowbase + (size_t)(cc1 >> 5) * (NTOK * DDIM) + (cc1 & 31)) = s1;
        *(uint4*)(qkvdst + rowbase + (size_t)(cc2 >> 5) * (NTOK * DDIM) + (cc2 & 31)) = s2;
      } else {
        *(uint4*)(o0 + rowbase + cb + 8 * khalf) = s1;
        *(uint4*)(o0 + rowbase + cb + 16 + 8 * khalf) = s2;
      }
    }
  }
}

// ---------------- attention: one wave per (window, head), in-register softmax ----------------
__global__ __launch_bounds__(64) void attn_k(
    const u16* __restrict__ qb, const u16* __restrict__ kb, const u16* __restrict__ vb,
    const float* __restrict__ bias16, const float* __restrict__ scale,
    const float* __restrict__ amask, u16* __restrict__ attn_out)
{
  __shared__ u16 Pmat[64][72];   // bf16 P (unnormalized), 144B rows (16B-aligned)
  __shared__ u16 vT[32][72];     // V transposed [d][tok]

  int bh = blockIdx.x;
  int b_ = bh >> 4, h = bh & 15;
  int wi = b_ & 63;
  int lane = threadIdx.x;
  int l15 = lane & 15, quad = lane >> 4;
  const u16* qs = qb + (size_t)bh * (NTOK * DDIM);
  const u16* ks = kb + (size_t)bh * (NTOK * DDIM);
  const u16* vs = vb + (size_t)bh * (NTOK * DDIM);

  bf16x8 qf[4], kf[4];
  #pragma unroll
  for (int mt = 0; mt < 4; mt++) {
    qf[mt] = *(const bf16x8*)(qs + (mt * 16 + l15) * DDIM + quad * 8);
    kf[mt] = *(const bf16x8*)(ks + (mt * 16 + l15) * DDIM + quad * 8);
  }
  // fused cosine normalization: lanes {l15, +16, +32, +48} share a row
  #pragma unroll
  for (int mt = 0; mt < 4; mt++) {
    float sq = 0.f, sk = 0.f;
    #pragma unroll
    for (int jj = 0; jj < 8; jj++) {
      float a = bf2f((u16)qf[mt][jj]); sq += a * a;
      float b = bf2f((u16)kf[mt][jj]); sk += b * b;
    }
    sq += __shfl_xor(sq, 16); sq += __shfl_xor(sq, 32);
    sk += __shfl_xor(sk, 16); sk += __shfl_xor(sk, 32);
    float iq = 1.f / fmaxf(sqrtf(sq), 1e-12f);
    float ik = 1.f / fmaxf(sqrtf(sk), 1e-12f);
    #pragma unroll
    for (int jj = 0; jj < 8; jj++) {
      qf[mt][jj] = (short)f2bf(bf2f((u16)qf[mt][jj]) * iq);
      kf[mt][jj] = (short)f2bf(bf2f((u16)kf[mt][jj]) * ik);
    }
  }
  // S = qn @ kn^T (in registers)
  f32x4 s[4][4];
  #pragma unroll
  for (int mt = 0; mt < 4; mt++)
    #pragma unroll
    for (int nt = 0; nt < 4; nt++) {
      f32x4 c = {0.f, 0.f, 0.f, 0.f};
      s[mt][nt] = __builtin_amdgcn_mfma_f32_16x16x32_bf16(qf[mt], kf[nt], c, 0, 0, 0);
    }
  // stage V^T
  #pragma unroll
  for (int d8 = 0; d8 < 4; d8++) {
    bf16x8 vv = *(const bf16x8*)(vs + lane * DDIM + d8 * 8);
    #pragma unroll
    for (int jj = 0; jj < 8; jj++) vT[d8 * 8 + jj][lane] = (u16)vv[jj];
  }

  // in-register softmax: row = mt*16+quad*4+i (16 lanes/row across l15)
  float sc = scale[h];
  float rinv[4][4];
  const float* bbase = bias16 + (size_t)h * 4096;
  const float* mbase = amask + (size_t)wi * 4096;
  #pragma unroll
  for (int mt = 0; mt < 4; mt++) {
    #pragma unroll
    for (int i = 0; i < 4; i++) {
      int row = mt * 16 + quad * 4 + i;
      const float* bro = bbase + row * 64;
      const float* mro = mbase + row * 64;
      float p[4];
      float mx = -1e30f;
      #pragma unroll
      for (int nt = 0; nt < 4; nt++) {
        int col = nt * 16 + l15;
        float vv = s[mt][nt][i] * sc + bro[col] + mro[col];
        p[nt] = vv;
        mx = fmaxf(mx, vv);
      }
      mx = fmaxf(mx, __shfl_xor(mx, 1));
      mx = fmaxf(mx, __shfl_xor(mx, 2));
      mx = fmaxf(mx, __shfl_xor(mx, 4));
      mx = fmaxf(mx, __shfl_xor(mx, 8));
      float sum = 0.f;
      #pragma unroll
      for (int nt = 0; nt < 4; nt++) {
        float e = __expf(p[nt] - mx);
        p[nt] = e;
        sum += e;
      }
      sum += __shfl_xor(sum, 1);
      sum += __shfl_xor(sum, 2);
      sum += __shfl_xor(sum, 4);
      sum += __shfl_xor(sum, 8);
      rinv[mt][i] = 1.f / sum;
      #pragma unroll
      for (int nt = 0; nt < 4; nt++)
        Pmat[row][nt * 16 + l15] = f2bf(p[nt]);
    }
  }
  __syncthreads();

  // O = P @ V (1/sum folded into epilogue)
  f32x4 oacc[4][2] = {};
  #pragma unroll
  for (int ks2 = 0; ks2 < 2; ks2++) {
    bf16x8 pf[4], vf[2];
    #pragma unroll
    for (int mt = 0; mt < 4; mt++)
      pf[mt] = *(const bf16x8*)&Pmat[mt * 16 + l15][ks2 * 32 + quad * 8];
    #pragma unroll
    for (int nt = 0; nt < 2; nt++)
      vf[nt] = *(const bf16x8*)&vT[nt * 16 + l15][ks2 * 32 + quad * 8];
    #pragma unroll
    for (int mt = 0; mt < 4; mt++)
      #pragma unroll
      for (int nt = 0; nt < 2; nt++)
        oacc[mt][nt] = __builtin_amdgcn_mfma_f32_16x16x32_bf16(pf[mt], vf[nt], oacc[mt][nt], 0, 0, 0);
  }
  #pragma unroll
  for (int mt = 0; mt < 4; mt++)
    #pragma unroll
    for (int nt = 0; nt < 2; nt++)
      #pragma unroll
      for (int i = 0; i < 4; i++) {
        int n = mt * 16 + quad * 4 + i;
        int d = nt * 16 + l15;
        float val = oacc[mt][nt][i] * rinv[mt][i];
        attn_out[(size_t)(b_ * 64 + n) * CCH + h * DDIM + d] = f2bf(val);
      }
}

// ---------------- LayerNorm + residual kernels (one wave per row) ----------------
__global__ __launch_bounds__(256) void ln_res_k(
    const float* __restrict__ xin, const u16* __restrict__ pin,
    const float* __restrict__ gam, const float* __restrict__ bet,
    float* __restrict__ x1f, u16* __restrict__ x1b)
{
  int row = blockIdx.x * 4 + (threadIdx.x >> 6);
  int lane = threadIdx.x & 63;
  size_t base = (size_t)row * CCH + lane * 8;
  uint4 u = *(const uint4*)(pin + base);
  unsigned w[4] = {u.x, u.y, u.z, u.w};
  float pv[8];
  #pragma unroll
  for (int j = 0; j < 4; j++) {
    pv[j * 2] = bf2f(w[j] & 0xffffu);
    pv[j * 2 + 1] = bf2f(w[j] >> 16);
  }
  float4 x0 = *(const float4*)(xin + base);
  float4 x1 = *(const float4*)(xin + base + 4);
  float xr[8] = {x0.x, x0.y, x0.z, x0.w, x1.x, x1.y, x1.z, x1.w};
  float s = 0.f, sq = 0.f;
  #pragma unroll
  for (int j = 0; j < 8; j++) { s += pv[j]; sq += pv[j] * pv[j]; }
  #pragma unroll
  for (int o = 32; o > 0; o >>= 1) { s += __shfl_xor(s, o, 64); sq += __shfl_xor(sq, o, 64); }
  float mean = s * (1.0f / 512.0f);
  float var = sq * (1.0f / 512.0f) - mean * mean;
  float rstd = rsqrtf(var + 1e-5f);
  float4 g0 = *(const float4*)(gam + lane * 8);
  float4 g1 = *(const float4*)(gam + lane * 8 + 4);
  float4 b0 = *(const float4*)(bet + lane * 8);
  float4 b1 = *(const float4*)(bet + lane * 8 + 4);
  float gg[8] = {g0.x, g0.y, g0.z, g0.w, g1.x, g1.y, g1.z, g1.w};
  float bb[8] = {b0.x, b0.y, b0.z, b0.w, b1.x, b1.y, b1.z, b1.w};
  float val[8];
  #pragma unroll
  for (int j = 0; j < 8; j++)
    val[j] = xr[j] + (pv[j] - mean) * rstd * gg[j] + bb[j];
  *(float4*)(x1f + base)     = make_float4(val[0], val[1], val[2], val[3]);
  *(float4*)(x1f + base + 4) = make_float4(val[4], val[5], val[6], val[7]);
  *(uint4*)(x1b + base) = make_uint4(cvtpk(val[0], val[1]), cvtpk(val[2], val[3]),
                                     cvtpk(val[4], val[5]), cvtpk(val[6], val[7]));
}

__global__ __launch_bounds__(256) void ln_fin_k(
    const u16* __restrict__ mlp, const float* __restrict__ gam,
    const float* __restrict__ bet, float* __restrict__ io)
{
  int row = blockIdx.x * 4 + (threadIdx.x >> 6);
  int lane = threadIdx.x & 63;
  size_t base = (size_t)row * CCH + lane * 8;
  uint4 u = *(const uint4*)(mlp + base);
  unsigned w[4] = {u.x, u.y, u.z, u.w};
  float pv[8];
  #pragma unroll
  for (int j = 0; j < 4; j++) {
    pv[j * 2] = bf2f(w[j] & 0xffffu);
    pv[j * 2 + 1] = bf2f(w[j] >> 16);
  }
  float s = 0.f, sq = 0.f;
  #pragma unroll
  for (int j = 0; j < 8; j++) { s += pv[j]; sq += pv[j] * pv[j]; }
  #pragma unroll
  for (int o = 32; o > 0; o >>= 1) { s += __shfl_xor(s, o, 64); sq += __shfl_xor(sq, o, 64); }
  float mean = s * (1.0f / 512.0f);
  float var = sq * (1.0f / 512.0f) - mean * mean;
  float rstd = rsqrtf(var + 1e-5f);
  float4 g0 = *(const float4*)(gam + lane * 8);
  float4 g1 = *(const float4*)(gam + lane * 8 + 4);
  float4 b0 = *(const float4*)(bet + lane * 8);
  float4 b1 = *(const float4*)(bet + lane * 8 + 4);
  float gg[8] = {g0.x, g0.y, g0.z, g0.w, g1.x, g1.y, g1.z, g1.w};
  float bb[8] = {b0.x, b0.y, b0.z, b0.w, b1.x, b1.y, b1.z, b1.w};
  float4 i0 = *(const float4*)(io + base);
  float4 i1 = *(const float4*)(io + base + 4);
  float iv[8] = {i0.x, i0.y, i0.z, i0.w, i1.x, i1.y, i1.z, i1.w};
  float out[8];
  #pragma unroll
  for (int j = 0; j < 8; j++)
    out[j] = iv[j] + (pv[j] - mean) * rstd * gg[j] + bb[j];
  *(float4*)(io + base)     = make_float4(out[0], out[1], out[2], out[3]);
  *(float4*)(io + base + 4) = make_float4(out[4], out[5], out[6], out[7]);
}

// ---------------- launcher ----------------
#define OFF_Q     ((size_t)0)
#define OFF_K     ((size_t)67108864)
#define OFF_V     ((size_t)134217728)
#define OFF_ATTN  ((size_t)201326592)
#define OFF_X1B   ((size_t)268435456)
#define OFF_WQKV  ((size_t)335544320)
#define OFF_WPROJ ((size_t)337117184)
#define OFF_WFC1  ((size_t)337641472)
#define OFF_WFC2  ((size_t)339738624)
#define OFF_T2    ((size_t)341835776)
#define OFF_B16   ((size_t)341852160)
#define OFF_SC    ((size_t)342114304)

extern "C" void kernel_launch(void* const* d_in, const int* in_sizes, int n_in,
                              void* d_out, int out_size, void* d_ws, size_t ws_size,
                              hipStream_t stream) {
  const float* x        = (const float*)d_in[0];
  const float* qkv_w    = (const float*)d_in[1];
  const float* q_bias   = (const float*)d_in[2];
  const float* v_bias   = (const float*)d_in[3];
  const float* lscale   = (const float*)d_in[4];
  const float* cpb_w1   = (const float*)d_in[5];
  const float* cpb_b1   = (const float*)d_in[6];
  const float* cpb_w2   = (const float*)d_in[7];
  const float* proj_w   = (const float*)d_in[8];
  const float* proj_b   = (const float*)d_in[9];
  const float* n1g      = (const float*)d_in[10];
  const float* n1b      = (const float*)d_in[11];
  const float* n2g      = (const float*)d_in[12];
  const float* n2b      = (const float*)d_in[13];
  const float* fc1_w    = (const float*)d_in[14];
  const float* fc1_b    = (const float*)d_in[15];
  const float* fc2_w    = (const float*)d_in[16];
  const float* fc2_b    = (const float*)d_in[17];
  const float* ctab     = (const float*)d_in[18];
  const float* amask    = (const float*)d_in[19];
  const int*   rpi      = (const int*)d_in[20];

  char* ws = (char*)d_ws;
  float* outp = (float*)d_out;

  u16*   q_buf    = (u16*)(ws + OFF_Q);
  u16*   k_buf    = (u16*)(ws + OFF_K);
  u16*   v_buf    = (u16*)(ws + OFF_V);
  u16*   proj_out = (u16*)(ws + OFF_Q);     // reuse R0 (bf16 now)
  u16*   hid      = (u16*)(ws + OFF_Q);     // reuse R0 (half-batch)
  u16*   xw       = (u16*)(ws + OFF_ATTN);  // R1 (dead after QKV gemm)
  u16*   attn_out = (u16*)(ws + OFF_ATTN);
  u16*   mlp_out  = (u16*)(ws + OFF_ATTN);
  u16*   x1b      = (u16*)(ws + OFF_X1B);
  u16*   wqkv     = (u16*)(ws + OFF_WQKV);
  u16*   wproj    = (u16*)(ws + OFF_WPROJ);
  u16*   wfc1     = (u16*)(ws + OFF_WFC1);
  u16*   wfc2     = (u16*)(ws + OFF_WFC2);
  float* t2       = (float*)(ws + OFF_T2);
  float* b16      = (float*)(ws + OFF_B16);
  float* scbuf    = (float*)(ws + OFF_SC);

  cvt_k<<<(1536 * 512 + 255) / 256, 256, 0, stream>>>(qkv_w, wqkv, 1536 * 512);
  cvt_k<<<(512 * 512 + 255) / 256, 256, 0, stream>>>(proj_w, wproj, 512 * 512);
  cvt_k<<<(2048 * 512 + 255) / 256, 256, 0, stream>>>(fc1_w, wfc1, 2048 * 512);
  cvt_k<<<(512 * 2048 + 255) / 256, 256, 0, stream>>>(fc2_w, wfc2, 512 * 2048);
  cpb_k<<<15, 256, 0, stream>>>(ctab, cpb_w1, cpb_b1, cpb_w2, t2);
  bias_k<<<256, 256, 0, stream>>>(t2, rpi, b16);
  scale_k<<<1, 64, 0, stream>>>(lscale, scbuf);

  // x -> xw (bf16, shifted-window order)
  xw_k<<<MTOT * 64 / 256, 256, 0, stream>>>(x, xw);
  // QKV: M=65536 (256 m-tiles), N=1536 (12 n-tiles)
  gemm256_k<0, 12><<<256 * 12, 512, 0, stream>>>(
      xw, wqkv, nullptr, q_bias, v_bias, q_buf, k_buf, v_buf, 512, 32);
  // attention (fused cosine norm, in-register softmax)
  attn_k<<<BWIN * HEADS, 64, 0, stream>>>(q_buf, k_buf, v_buf, b16, scbuf, amask, attn_out);
  // proj: N=512 (4 n-tiles), bf16 out, window-reverse fused
  gemm256_k<1, 4><<<256 * 4, 512, 0, stream>>>(
      attn_out, wproj, proj_b, nullptr, nullptr, proj_out, nullptr, nullptr, 512, 32);
  // x1 = x + LN1(proj_out)
  ln_res_k<<<MTOT / 4, 256, 0, stream>>>(x, proj_out, n1g, n1b, outp, x1b);
  // MLP in two row-halves
  for (int half = 0; half < 2; half++) {
    const u16* a1 = x1b + (size_t)half * (MTOT / 2) * CCH;
    u16* m1 = mlp_out + (size_t)half * (MTOT / 2) * CCH;
    gemm256_k<2, 16><<<128 * 16, 512, 0, stream>>>(
        a1, wfc1, fc1_b, nullptr, nullptr, hid, nullptr, nullptr, 512, 16);
    gemm256_k<3, 4><<<128 * 4, 512, 0, stream>>>(
        hid, wfc2, fc2_b, nullptr, nullptr, m1, nullptr, nullptr, 2048, 16);
  }
  // out = x1 + LN2(mlp)
  ln_fin_k<<<MTOT / 4, 256, 0, stream>>>(mlp_out, n2g, n2b, outp);
}

// Round 6
// 1220.597 us; speedup vs baseline: 1.2415x; 1.2415x over previous
//
#include <hip/hip_runtime.h>
#include <hip/hip_bf16.h>
#include <math.h>

// ---- problem constants ----
#define BB     16
#define HH     64
#define WWID   64
#define CCH    512
#define HEADS  16
#define NTOK   64
#define DDIM   32
#define NWIN   64
#define LL     (HH*WWID)       // 4096
#define MTOT   (BB*LL)         // 65536 rows
#define BWIN   (BB*NWIN)       // 1024 windows
#define HIDN   2048
#define SHIFT_ 4

typedef unsigned short u16;
using bf16x8 = __attribute__((ext_vector_type(8))) short;   // 8 bf16 (4 VGPRs)
using f32x4  = __attribute__((ext_vector_type(4))) float;
using f32x16 = __attribute__((ext_vector_type(16))) float;

__device__ __forceinline__ u16 f2bf(float f) {
  union { float f; unsigned u; } v; v.f = f;
  unsigned r = v.u + 0x7fffu + ((v.u >> 16) & 1u);   // RNE
  return (u16)(r >> 16);
}
__device__ __forceinline__ float bf2f(unsigned h) {
  union { unsigned u; float f; } v; v.u = h << 16;
  return v.f;
}
// packed f32x2 -> bf16x2 (hardware RNE, 1 instr for 2 elems)
__device__ __forceinline__ unsigned cvtpk(float lo, float hi) {
  unsigned r;
  asm("v_cvt_pk_bf16_f32 %0, %1, %2" : "=v"(r) : "v"(lo), "v"(hi));
  return r;
}
// fast GELU: x*sigmoid(1.5958(x+0.044715x^3)); |err| ~1e-3 << bf16 quant noise
__device__ __forceinline__ float gelu_f(float v) {
  float v3 = v * v * v;
  float y = 1.5957691216057308f * v + 0.0713548162726009f * v3;
  return v / (1.f + __expf(-y));
}

__device__ __forceinline__ void gload16(const void* g, void* l) {
  __builtin_amdgcn_global_load_lds((const __attribute__((address_space(1))) void*)g,
                                   (__attribute__((address_space(3))) void*)l, 16, 0, 0);
}

// shifted-window mapping: windowed token (b_, n) -> original row index in x
__device__ __forceinline__ int win2orig(int b_, int n) {
  int b = b_ >> 6, wi = b_ & 63;
  int hs = (wi >> 3) * 8 + (n >> 3);
  int ws = (wi & 7) * 8 + (n & 7);
  int hq = (hs + SHIFT_) & 63;
  int wq = (ws + SHIFT_) & 63;
  return b * LL + hq * WWID + wq;
}

// ---------------- tiny setup kernels ----------------
__global__ void cvt_k(const float* __restrict__ s, u16* __restrict__ d, int n) {
  int i = blockIdx.x * 256 + threadIdx.x;
  if (i < n) d[i] = f2bf(s[i]);
}

__global__ void cpb_k(const float* __restrict__ ct, const float* __restrict__ w1,
                      const float* __restrict__ b1, const float* __restrict__ w2,
                      float* __restrict__ t2) {
  int t = blockIdx.x * 256 + threadIdx.x;
  if (t >= 225 * 16) return;
  int rr = t >> 4, h = t & 15;
  float c0 = ct[rr * 2], c1 = ct[rr * 2 + 1];
  float acc = 0.f;
  for (int j = 0; j < 512; j++) {
    float hv = fmaxf(w1[j * 2] * c0 + w1[j * 2 + 1] * c1 + b1[j], 0.f);
    acc += hv * w2[h * 512 + j];
  }
  t2[t] = acc;
}

__global__ void bias_k(const float* __restrict__ t2, const int* __restrict__ rpi,
                       float* __restrict__ b16) {
  int t = blockIdx.x * 256 + threadIdx.x;   // h*4096 + n*64 + m
  int nm = t & 4095;
  int h = t >> 12;
  float v = t2[rpi[nm] * 16 + h];
  b16[t] = 16.0f / (1.0f + __expf(-v));
}

__global__ void scale_k(const float* __restrict__ ls, float* __restrict__ sc) {
  int t = threadIdx.x;
  if (t < HEADS) sc[t] = __expf(fminf(ls[t], 4.6051701859880914f)); // ln(100)
}

// x (fp32) -> xw (bf16) in shifted-window token order [b_*64+n][512]
__global__ __launch_bounds__(256) void xw_k(const float* __restrict__ x, u16* __restrict__ xw) {
  int t = blockIdx.x * 256 + threadIdx.x;
  int row = t >> 6;
  int col = (t & 63) * 8;
  const float* src = x + (size_t)win2orig(row >> 6, row & 63) * CCH + col;
  float4 a = *(const float4*)src;
  float4 b = *(const float4*)(src + 4);
  uint4 o = make_uint4(cvtpk(a.x, a.y), cvtpk(a.z, a.w),
                       cvtpk(b.x, b.y), cvtpk(b.z, b.w));
  *(uint4*)(xw + (size_t)row * CCH + col) = o;
}

// ---------------- MFMA GEMM, 256x128 block tile, 32x32x16 MFMA ----------------
// A bf16 [M][K], B bf16 [N][K] -> C = A @ B^T.  4 waves (256 thr),
// wave tile 128x64, acc[4][2] (128 acc regs) -- R3-verified geometry.
// A through LDS (3 buffers x 16KB, depth-2 gload_lds pipeline, swizzled).
// B DIRECT-TO-REGISTER, SOFTWARE-PIPELINED (ping-pong): iteration it issues
//   B(it+1) loads right after the barrier and computes with B(it) already in
//   regs -> B's L2 latency hides under 16 MFMAs + 8 ds_reads. (R5 bug: B was
//   loaded and consumed in the same iteration -> serial L2 latency, 16% util.)
// vmcnt: stage=4 gload_lds/tile, B=4 loads/iter. Steady wait vmcnt(8)
//   (allows B(it)+stage(it+1) in flight, guarantees stage(it) done);
//   last iter vmcnt(4). Compiler inserts exact waits for B-reg use.
// mfma(b,a): acc holds C^T; lane owns a fixed output row, regs walk N.
// Epilogue: v_permlane32_swap_b32 assembles 8 contiguous channels/lane ->
//   16B uint4 stores; khalf pair covers full 32B sectors.
// A LDS swizzle: s(row) = (row + (row>>2)) & 3, chunk c at c^s(row) via
//   pre-swizzled global source addr (LDS dest linear). 0 bank conflicts (R3).
// XCD swizzle: lin%8 -> XCD, contiguous M-chunk per XCD for A-tile L2 reuse.
// MODE 0: QKV (epi: +q/v bias, scatter to [b_][h][n][d] bf16)
// MODE 1: proj (epi: +proj_b, bf16 scatter to original token order)
// MODE 2: fc1  (epi: +fc1_b, fast GELU, bf16 ld=HIDN)
// MODE 3: fc2  (epi: +fc2_b, bf16 ld=CCH)
template<int MODE, int NBN>
__global__ __launch_bounds__(256, 2) void gemm256_k(
    const u16* __restrict__ A, const u16* __restrict__ Bw,
    const float* __restrict__ bias,
    const float* __restrict__ qbias, const float* __restrict__ vbias,
    u16* __restrict__ o0, u16* __restrict__ o1, u16* __restrict__ o2,
    int K, int mchunk)
{
  // 3 A-buffers: 256 rows x 32 k x 2B = 16 KB each, 48 KB total
  __shared__ __align__(16) u16 smem[3 * 8192];
  const int t = threadIdx.x;
  const int lin = blockIdx.x;
  const int xcd = lin & 7;
  const int j = lin >> 3;
  const int m0 = (xcd * mchunk + j / NBN) * 256;
  const int n0 = (j % NBN) * 128;
  const int lane = t & 63;
  const int wv = t >> 6;          // 0..3
  const int wm = (wv & 1) * 128;
  const int wn = (wv >> 1) * 64;
  const int l31 = lane & 31;
  const int khalf = lane >> 5;    // 0/1

  // A staging: chunk c = i*256 + t; row = c>>2 = i*64 + (t>>2);
  // s(row) = ((t>>2)+(t>>4)) & 3 (i-independent since i*80 % 4 == 0).
  const int sstg = (((t >> 2) + (t >> 4)) & 3);
  const int swcol = (((t & 3) ^ sstg) * 8);
  const u16* aP[4]; int aL[4];
  #pragma unroll
  for (int i = 0; i < 4; i++) {
    aP[i] = A + (size_t)(m0 + i * 64 + (t >> 2)) * K + swcol;
    aL[i] = i * 4096 + wv * 1024;
  }
  // B fragment pointers (per-lane, global): row = n0+wn+nt*32+l31
  const u16* bReg[2];
  #pragma unroll
  for (int nt = 0; nt < 2; nt++)
    bReg[nt] = Bw + (size_t)(n0 + wn + nt * 32 + l31) * K + khalf * 8;

  f32x16 acc[4][2] = {};

  auto stage = [&](int k0, int bi) {
    char* base = (char*)smem + bi * 16384;
    #pragma unroll
    for (int i = 0; i < 4; i++) gload16(aP[i] + k0, base + aL[i]);
  };

  const int NT = K >> 5;
  stage(0, 0);
  stage(32, 1);
  // prologue B(0) into ping buffer
  bf16x8 bfA[2][2], bfB[2][2];
  #pragma unroll
  for (int nt = 0; nt < 2; nt++)
    #pragma unroll
    for (int ks = 0; ks < 2; ks++)
      bfA[nt][ks] = *(const bf16x8*)(bReg[nt] + ks * 16);

  // read-side swizzle: row = wm + mt*32 + l31 -> s depends only on l31
  const int srd = ((l31 & 3) + ((l31 >> 2) & 3)) & 3;

  auto body = [&](int it, bf16x8 (&cur)[2][2], bf16x8 (&nxt)[2][2]) {
    // guarantee stage(it) retired; keep B(it)[in regs' loads] + stage(it+1) in flight
    if (it + 1 < NT) asm volatile("s_waitcnt vmcnt(8)" ::: "memory");
    else             asm volatile("s_waitcnt vmcnt(4)" ::: "memory");
    __builtin_amdgcn_s_barrier();       // buffer it ready; reads of it-1 done
    asm volatile("" ::: "memory");

    // issue B(it+1) immediately -> full iteration of latency slack
    if (it + 1 < NT) {
      const int kn = (it + 1) << 5;
      #pragma unroll
      for (int nt = 0; nt < 2; nt++)
        #pragma unroll
        for (int ks = 0; ks < 2; ks++)
          nxt[nt][ks] = *(const bf16x8*)(bReg[nt] + kn + ks * 16);
    }
    if (it + 2 < NT) stage((it + 2) << 5, (it + 2) % 3);

    const u16* Ab = (const u16*)((const char*)smem + (it % 3) * 16384);
    #pragma unroll
    for (int ks = 0; ks < 2; ks++) {
      const int kc = (ks * 2 + khalf) ^ srd;   // swizzled k-chunk (A only)
      bf16x8 af[4];
      #pragma unroll
      for (int mt = 0; mt < 4; mt++)
        af[mt] = *(const bf16x8*)&Ab[(wm + mt * 32 + l31) * 32 + kc * 8];
      #pragma unroll
      for (int mt = 0; mt < 4; mt++)
        #pragma unroll
        for (int nt = 0; nt < 2; nt++)
          acc[mt][nt] = __builtin_amdgcn_mfma_f32_32x32x16_bf16(cur[nt][ks], af[mt], acc[mt][nt], 0, 0, 0);
    }
  };

  for (int it2 = 0; it2 < NT; it2 += 2) {
    body(it2, bfA, bfB);
    body(it2 + 1, bfB, bfA);
  }

  // epilogue: acc holds C^T tiles.
  //   row = m0+wm+mt*32+l31 (fixed/lane); own cols = cb + 8g + 4*khalf (+0..3)
  const int part = n0 >> 9;   // MODE 0 only (tile never spans q/k/v parts)
  u16* qkvdst = (MODE == 0) ? (part == 0 ? o0 : (part == 1 ? o1 : o2)) : o0;
  #pragma unroll
  for (int mt = 0; mt < 4; mt++) {
    const int grow = m0 + wm + mt * 32 + l31;
    size_t rowbase;
    if (MODE == 0) {
      int b_ = grow >> 6, n = grow & 63;
      rowbase = ((size_t)b_ * HEADS) * (NTOK * DDIM) + (size_t)n * DDIM;
    } else if (MODE == 1) {
      rowbase = (size_t)win2orig(grow >> 6, grow & 63) * CCH;
    } else if (MODE == 2) {
      rowbase = (size_t)grow * HIDN;
    } else {
      rowbase = (size_t)grow * CCH;
    }
    #pragma unroll
    for (int nt = 0; nt < 2; nt++) {
      const int cb = n0 + wn + nt * 32;          // 32-aligned channel base
      unsigned U[4], W[4];
      #pragma unroll
      for (int g = 0; g < 4; g++) {
        const int nb = cb + 8 * g + 4 * khalf;
        float v0 = acc[mt][nt][g * 4 + 0];
        float v1 = acc[mt][nt][g * 4 + 1];
        float v2 = acc[mt][nt][g * 4 + 2];
        float v3 = acc[mt][nt][g * 4 + 3];
        if (MODE == 0) {
          const int cc = nb & 511;
          if (part == 0) {
            float4 b4 = *(const float4*)(qbias + cc);
            v0 += b4.x; v1 += b4.y; v2 += b4.z; v3 += b4.w;
          } else if (part == 2) {
            float4 b4 = *(const float4*)(vbias + cc);
            v0 += b4.x; v1 += b4.y; v2 += b4.z; v3 += b4.w;
          }
        } else {
          float4 b4 = *(const float4*)(bias + nb);
          v0 += b4.x; v1 += b4.y; v2 += b4.z; v3 += b4.w;
          if (MODE == 2) {
            v0 = gelu_f(v0); v1 = gelu_f(v1); v2 = gelu_f(v2); v3 = gelu_f(v3);
          }
        }
        U[g] = cvtpk(v0, v1);
        W[g] = cvtpk(v2, v3);
      }
      // A.high <-> B.low swaps: assemble 8 contiguous channels per lane
      asm volatile("v_permlane32_swap_b32 %0, %1" : "+v"(U[0]), "+v"(U[1]));
      asm volatile("v_permlane32_swap_b32 %0, %1" : "+v"(W[0]), "+v"(W[1]));
      asm volatile("v_permlane32_swap_b32 %0, %1" : "+v"(U[2]), "+v"(U[3]));
      asm volatile("v_permlane32_swap_b32 %0, %1" : "+v"(W[2]), "+v"(W[3]));
      uint4 s1 = make_uint4(U[0], W[0], U[1], W[1]);   // cols [cb+8k, cb+8k+8)
      uint4 s2 = make_uint4(U[2], W[2], U[3], W[3]);   // cols [cb+16+8k, +8)
      if (MODE == 0) {
        const int cc1 = (cb & 511) + 8 * khalf;
        const int cc2 = cc1 + 16;
        *(uint4*)(qkvdst + rowbase + (size_t)(cc1 >> 5) * (NTOK * DDIM) + (cc1 & 31)) = s1;
        *(uint4*)(qkvdst + rowbase + (size_t)(cc2 >> 5) * (NTOK * DDIM) + (cc2 & 31)) = s2;
      } else {
        *(uint4*)(o0 + rowbase + cb + 8 * khalf) = s1;
        *(uint4*)(o0 + rowbase + cb + 16 + 8 * khalf) = s2;
      }
    }
  }
}

// ---------------- attention: one wave per (window, head), in-register softmax ----------------
__global__ __launch_bounds__(64) void attn_k(
    const u16* __restrict__ qb, const u16* __restrict__ kb, const u16* __restrict__ vb,
    const float* __restrict__ bias16, const float* __restrict__ scale,
    const float* __restrict__ amask, u16* __restrict__ attn_out)
{
  __shared__ u16 Pmat[64][72];   // bf16 P (unnormalized), 144B rows (16B-aligned)
  __shared__ u16 vT[32][72];     // V transposed [d][tok]

  int bh = blockIdx.x;
  int b_ = bh >> 4, h = bh & 15;
  int wi = b_ & 63;
  int lane = threadIdx.x;
  int l15 = lane & 15, quad = lane >> 4;
  const u16* qs = qb + (size_t)bh * (NTOK * DDIM);
  const u16* ks = kb + (size_t)bh * (NTOK * DDIM);
  const u16* vs = vb + (size_t)bh * (NTOK * DDIM);

  bf16x8 qf[4], kf[4];
  #pragma unroll
  for (int mt = 0; mt < 4; mt++) {
    qf[mt] = *(const bf16x8*)(qs + (mt * 16 + l15) * DDIM + quad * 8);
    kf[mt] = *(const bf16x8*)(ks + (mt * 16 + l15) * DDIM + quad * 8);
  }
  // fused cosine normalization: lanes {l15, +16, +32, +48} share a row
  #pragma unroll
  for (int mt = 0; mt < 4; mt++) {
    float sq = 0.f, sk = 0.f;
    #pragma unroll
    for (int jj = 0; jj < 8; jj++) {
      float a = bf2f((u16)qf[mt][jj]); sq += a * a;
      float b = bf2f((u16)kf[mt][jj]); sk += b * b;
    }
    sq += __shfl_xor(sq, 16); sq += __shfl_xor(sq, 32);
    sk += __shfl_xor(sk, 16); sk += __shfl_xor(sk, 32);
    float iq = 1.f / fmaxf(sqrtf(sq), 1e-12f);
    float ik = 1.f / fmaxf(sqrtf(sk), 1e-12f);
    #pragma unroll
    for (int jj = 0; jj < 8; jj++) {
      qf[mt][jj] = (short)f2bf(bf2f((u16)qf[mt][jj]) * iq);
      kf[mt][jj] = (short)f2bf(bf2f((u16)kf[mt][jj]) * ik);
    }
  }
  // S = qn @ kn^T (in registers)
  f32x4 s[4][4];
  #pragma unroll
  for (int mt = 0; mt < 4; mt++)
    #pragma unroll
    for (int nt = 0; nt < 4; nt++) {
      f32x4 c = {0.f, 0.f, 0.f, 0.f};
      s[mt][nt] = __builtin_amdgcn_mfma_f32_16x16x32_bf16(qf[mt], kf[nt], c, 0, 0, 0);
    }
  // stage V^T
  #pragma unroll
  for (int d8 = 0; d8 < 4; d8++) {
    bf16x8 vv = *(const bf16x8*)(vs + lane * DDIM + d8 * 8);
    #pragma unroll
    for (int jj = 0; jj < 8; jj++) vT[d8 * 8 + jj][lane] = (u16)vv[jj];
  }

  // in-register softmax: row = mt*16+quad*4+i (16 lanes/row across l15)
  float sc = scale[h];
  float rinv[4][4];
  const float* bbase = bias16 + (size_t)h * 4096;
  const float* mbase = amask + (size_t)wi * 4096;
  #pragma unroll
  for (int mt = 0; mt < 4; mt++) {
    #pragma unroll
    for (int i = 0; i < 4; i++) {
      int row = mt * 16 + quad * 4 + i;
      const float* bro = bbase + row * 64;
      const float* mro = mbase + row * 64;
      float p[4];
      float mx = -1e30f;
      #pragma unroll
      for (int nt = 0; nt < 4; nt++) {
        int col = nt * 16 + l15;
        float vv = s[mt][nt][i] * sc + bro[col] + mro[col];
        p[nt] = vv;
        mx = fmaxf(mx, vv);
      }
      mx = fmaxf(mx, __shfl_xor(mx, 1));
      mx = fmaxf(mx, __shfl_xor(mx, 2));
      mx = fmaxf(mx, __shfl_xor(mx, 4));
      mx = fmaxf(mx, __shfl_xor(mx, 8));
      float sum = 0.f;
      #pragma unroll
      for (int nt = 0; nt < 4; nt++) {
        float e = __expf(p[nt] - mx);
        p[nt] = e;
        sum += e;
      }
      sum += __shfl_xor(sum, 1);
      sum += __shfl_xor(sum, 2);
      sum += __shfl_xor(sum, 4);
      sum += __shfl_xor(sum, 8);
      rinv[mt][i] = 1.f / sum;
      #pragma unroll
      for (int nt = 0; nt < 4; nt++)
        Pmat[row][nt * 16 + l15] = f2bf(p[nt]);
    }
  }
  __syncthreads();

  // O = P @ V (1/sum folded into epilogue)
  f32x4 oacc[4][2] = {};
  #pragma unroll
  for (int ks2 = 0; ks2 < 2; ks2++) {
    bf16x8 pf[4], vf[2];
    #pragma unroll
    for (int mt = 0; mt < 4; mt++)
      pf[mt] = *(const bf16x8*)&Pmat[mt * 16 + l15][ks2 * 32 + quad * 8];
    #pragma unroll
    for (int nt = 0; nt < 2; nt++)
      vf[nt] = *(const bf16x8*)&vT[nt * 16 + l15][ks2 * 32 + quad * 8];
    #pragma unroll
    for (int mt = 0; mt < 4; mt++)
      #pragma unroll
      for (int nt = 0; nt < 2; nt++)
        oacc[mt][nt] = __builtin_amdgcn_mfma_f32_16x16x32_bf16(pf[mt], vf[nt], oacc[mt][nt], 0, 0, 0);
  }
  #pragma unroll
  for (int mt = 0; mt < 4; mt++)
    #pragma unroll
    for (int nt = 0; nt < 2; nt++)
      #pragma unroll
      for (int i = 0; i < 4; i++) {
        int n = mt * 16 + quad * 4 + i;
        int d = nt * 16 + l15;
        float val = oacc[mt][nt][i] * rinv[mt][i];
        attn_out[(size_t)(b_ * 64 + n) * CCH + h * DDIM + d] = f2bf(val);
      }
}

// ---------------- LayerNorm + residual kernels (one wave per row) ----------------
__global__ __launch_bounds__(256) void ln_res_k(
    const float* __restrict__ xin, const u16* __restrict__ pin,
    const float* __restrict__ gam, const float* __restrict__ bet,
    float* __restrict__ x1f, u16* __restrict__ x1b)
{
  int row = blockIdx.x * 4 + (threadIdx.x >> 6);
  int lane = threadIdx.x & 63;
  size_t base = (size_t)row * CCH + lane * 8;
  uint4 u = *(const uint4*)(pin + base);
  unsigned w[4] = {u.x, u.y, u.z, u.w};
  float pv[8];
  #pragma unroll
  for (int j = 0; j < 4; j++) {
    pv[j * 2] = bf2f(w[j] & 0xffffu);
    pv[j * 2 + 1] = bf2f(w[j] >> 16);
  }
  float4 x0 = *(const float4*)(xin + base);
  float4 x1 = *(const float4*)(xin + base + 4);
  float xr[8] = {x0.x, x0.y, x0.z, x0.w, x1.x, x1.y, x1.z, x1.w};
  float s = 0.f, sq = 0.f;
  #pragma unroll
  for (int j = 0; j < 8; j++) { s += pv[j]; sq += pv[j] * pv[j]; }
  #pragma unroll
  for (int o = 32; o > 0; o >>= 1) { s += __shfl_xor(s, o, 64); sq += __shfl_xor(sq, o, 64); }
  float mean = s * (1.0f / 512.0f);
  float var = sq * (1.0f / 512.0f) - mean * mean;
  float rstd = rsqrtf(var + 1e-5f);
  float4 g0 = *(const float4*)(gam + lane * 8);
  float4 g1 = *(const float4*)(gam + lane * 8 + 4);
  float4 b0 = *(const float4*)(bet + lane * 8);
  float4 b1 = *(const float4*)(bet + lane * 8 + 4);
  float gg[8] = {g0.x, g0.y, g0.z, g0.w, g1.x, g1.y, g1.z, g1.w};
  float bb[8] = {b0.x, b0.y, b0.z, b0.w, b1.x, b1.y, b1.z, b1.w};
  float val[8];
  #pragma unroll
  for (int j = 0; j < 8; j++)
    val[j] = xr[j] + (pv[j] - mean) * rstd * gg[j] + bb[j];
  *(float4*)(x1f + base)     = make_float4(val[0], val[1], val[2], val[3]);
  *(float4*)(x1f + base + 4) = make_float4(val[4], val[5], val[6], val[7]);
  *(uint4*)(x1b + base) = make_uint4(cvtpk(val[0], val[1]), cvtpk(val[2], val[3]),
                                     cvtpk(val[4], val[5]), cvtpk(val[6], val[7]));
}

__global__ __launch_bounds__(256) void ln_fin_k(
    const u16* __restrict__ mlp, const float* __restrict__ gam,
    const float* __restrict__ bet, float* __restrict__ io)
{
  int row = blockIdx.x * 4 + (threadIdx.x >> 6);
  int lane = threadIdx.x & 63;
  size_t base = (size_t)row * CCH + lane * 8;
  uint4 u = *(const uint4*)(mlp + base);
  unsigned w[4] = {u.x, u.y, u.z, u.w};
  float pv[8];
  #pragma unroll
  for (int j = 0; j < 4; j++) {
    pv[j * 2] = bf2f(w[j] & 0xffffu);
    pv[j * 2 + 1] = bf2f(w[j] >> 16);
  }
  float s = 0.f, sq = 0.f;
  #pragma unroll
  for (int j = 0; j < 8; j++) { s += pv[j]; sq += pv[j] * pv[j]; }
  #pragma unroll
  for (int o = 32; o > 0; o >>= 1) { s += __shfl_xor(s, o, 64); sq += __shfl_xor(sq, o, 64); }
  float mean = s * (1.0f / 512.0f);
  float var = sq * (1.0f / 512.0f) - mean * mean;
  float rstd = rsqrtf(var + 1e-5f);
  float4 g0 = *(const float4*)(gam + lane * 8);
  float4 g1 = *(const float4*)(gam + lane * 8 + 4);
  float4 b0 = *(const float4*)(bet + lane * 8);
  float4 b1 = *(const float4*)(bet + lane * 8 + 4);
  float gg[8] = {g0.x, g0.y, g0.z, g0.w, g1.x, g1.y, g1.z, g1.w};
  float bb[8] = {b0.x, b0.y, b0.z, b0.w, b1.x, b1.y, b1.z, b1.w};
  float4 i0 = *(const float4*)(io + base);
  float4 i1 = *(const float4*)(io + base + 4);
  float iv[8] = {i0.x, i0.y, i0.z, i0.w, i1.x, i1.y, i1.z, i1.w};
  float out[8];
  #pragma unroll
  for (int j = 0; j < 8; j++)
    out[j] = iv[j] + (pv[j] - mean) * rstd * gg[j] + bb[j];
  *(float4*)(io + base)     = make_float4(out[0], out[1], out[2], out[3]);
  *(float4*)(io + base + 4) = make_float4(out[4], out[5], out[6], out[7]);
}

// ---------------- launcher ----------------
#define OFF_Q     ((size_t)0)
#define OFF_K     ((size_t)67108864)
#define OFF_V     ((size_t)134217728)
#define OFF_ATTN  ((size_t)201326592)
#define OFF_X1B   ((size_t)268435456)
#define OFF_WQKV  ((size_t)335544320)
#define OFF_WPROJ ((size_t)337117184)
#define OFF_WFC1  ((size_t)337641472)
#define OFF_WFC2  ((size_t)339738624)
#define OFF_T2    ((size_t)341835776)
#define OFF_B16   ((size_t)341852160)
#define OFF_SC    ((size_t)342114304)

extern "C" void kernel_launch(void* const* d_in, const int* in_sizes, int n_in,
                              void* d_out, int out_size, void* d_ws, size_t ws_size,
                              hipStream_t stream) {
  const float* x        = (const float*)d_in[0];
  const float* qkv_w    = (const float*)d_in[1];
  const float* q_bias   = (const float*)d_in[2];
  const float* v_bias   = (const float*)d_in[3];
  const float* lscale   = (const float*)d_in[4];
  const float* cpb_w1   = (const float*)d_in[5];
  const float* cpb_b1   = (const float*)d_in[6];
  const float* cpb_w2   = (const float*)d_in[7];
  const float* proj_w   = (const float*)d_in[8];
  const float* proj_b   = (const float*)d_in[9];
  const float* n1g      = (const float*)d_in[10];
  const float* n1b      = (const float*)d_in[11];
  const float* n2g      = (const float*)d_in[12];
  const float* n2b      = (const float*)d_in[13];
  const float* fc1_w    = (const float*)d_in[14];
  const float* fc1_b    = (const float*)d_in[15];
  const float* fc2_w    = (const float*)d_in[16];
  const float* fc2_b    = (const float*)d_in[17];
  const float* ctab     = (const float*)d_in[18];
  const float* amask    = (const float*)d_in[19];
  const int*   rpi      = (const int*)d_in[20];

  char* ws = (char*)d_ws;
  float* outp = (float*)d_out;

  u16*   q_buf    = (u16*)(ws + OFF_Q);
  u16*   k_buf    = (u16*)(ws + OFF_K);
  u16*   v_buf    = (u16*)(ws + OFF_V);
  u16*   proj_out = (u16*)(ws + OFF_Q);     // reuse R0 (bf16 now)
  u16*   hid      = (u16*)(ws + OFF_Q);     // reuse R0 (half-batch)
  u16*   xw       = (u16*)(ws + OFF_ATTN);  // R1 (dead after QKV gemm)
  u16*   attn_out = (u16*)(ws + OFF_ATTN);
  u16*   mlp_out  = (u16*)(ws + OFF_ATTN);
  u16*   x1b      = (u16*)(ws + OFF_X1B);
  u16*   wqkv     = (u16*)(ws + OFF_WQKV);
  u16*   wproj    = (u16*)(ws + OFF_WPROJ);
  u16*   wfc1     = (u16*)(ws + OFF_WFC1);
  u16*   wfc2     = (u16*)(ws + OFF_WFC2);
  float* t2       = (float*)(ws + OFF_T2);
  float* b16      = (float*)(ws + OFF_B16);
  float* scbuf    = (float*)(ws + OFF_SC);

  cvt_k<<<(1536 * 512 + 255) / 256, 256, 0, stream>>>(qkv_w, wqkv, 1536 * 512);
  cvt_k<<<(512 * 512 + 255) / 256, 256, 0, stream>>>(proj_w, wproj, 512 * 512);
  cvt_k<<<(2048 * 512 + 255) / 256, 256, 0, stream>>>(fc1_w, wfc1, 2048 * 512);
  cvt_k<<<(512 * 2048 + 255) / 256, 256, 0, stream>>>(fc2_w, wfc2, 512 * 2048);
  cpb_k<<<15, 256, 0, stream>>>(ctab, cpb_w1, cpb_b1, cpb_w2, t2);
  bias_k<<<256, 256, 0, stream>>>(t2, rpi, b16);
  scale_k<<<1, 64, 0, stream>>>(lscale, scbuf);

  // x -> xw (bf16, shifted-window order)
  xw_k<<<MTOT * 64 / 256, 256, 0, stream>>>(x, xw);
  // QKV: M=65536 (256 m-tiles), N=1536 (12 n-tiles)
  gemm256_k<0, 12><<<256 * 12, 256, 0, stream>>>(
      xw, wqkv, nullptr, q_bias, v_bias, q_buf, k_buf, v_buf, 512, 32);
  // attention (fused cosine norm, in-register softmax)
  attn_k<<<BWIN * HEADS, 64, 0, stream>>>(q_buf, k_buf, v_buf, b16, scbuf, amask, attn_out);
  // proj: N=512 (4 n-tiles), bf16 out, window-reverse fused
  gemm256_k<1, 4><<<256 * 4, 256, 0, stream>>>(
      attn_out, wproj, proj_b, nullptr, nullptr, proj_out, nullptr, nullptr, 512, 32);
  // x1 = x + LN1(proj_out)
  ln_res_k<<<MTOT / 4, 256, 0, stream>>>(x, proj_out, n1g, n1b, outp, x1b);
  // MLP in two row-halves
  for (int half = 0; half < 2; half++) {
    const u16* a1 = x1b + (size_t)half * (MTOT / 2) * CCH;
    u16* m1 = mlp_out + (size_t)half * (MTOT / 2) * CCH;
    gemm256_k<2, 16><<<128 * 16, 256, 0, stream>>>(
        a1, wfc1, fc1_b, nullptr, nullptr, hid, nullptr, nullptr, 512, 16);
    gemm256_k<3, 4><<<128 * 4, 256, 0, stream>>>(
        hid, wfc2, fc2_b, nullptr, nullptr, m1, nullptr, nullptr, 2048, 16);
  }
  // out = x1 + LN2(mlp)
  ln_fin_k<<<MTOT / 4, 256, 0, stream>>>(mlp_out, n2g, n2b, outp);
}

// Round 7
// 1040.981 us; speedup vs baseline: 1.4558x; 1.1725x over previous
//
#include <hip/hip_runtime.h>
#include <hip/hip_bf16.h>
#include <math.h>

// ---- problem constants ----
#define BB     16
#define HH     64
#define WWID   64
#define CCH    512
#define HEADS  16
#define NTOK   64
#define DDIM   32
#define NWIN   64
#define LL     (HH*WWID)       // 4096
#define MTOT   (BB*LL)         // 65536 rows
#define BWIN   (BB*NWIN)       // 1024 windows
#define HIDN   2048
#define SHIFT_ 4

typedef unsigned short u16;
using bf16x8 = __attribute__((ext_vector_type(8))) short;   // 8 bf16 (4 VGPRs)
using f32x4  = __attribute__((ext_vector_type(4))) float;

__device__ __forceinline__ u16 f2bf(float f) {
  union { float f; unsigned u; } v; v.f = f;
  unsigned r = v.u + 0x7fffu + ((v.u >> 16) & 1u);   // RNE
  return (u16)(r >> 16);
}
__device__ __forceinline__ float bf2f(unsigned h) {
  union { unsigned u; float f; } v; v.u = h << 16;
  return v.f;
}
// packed f32x2 -> bf16x2 (hardware RNE, 1 instr for 2 elems)
__device__ __forceinline__ unsigned cvtpk(float lo, float hi) {
  unsigned r;
  asm("v_cvt_pk_bf16_f32 %0, %1, %2" : "=v"(r) : "v"(lo), "v"(hi));
  return r;
}
// fast GELU: x*sigmoid(1.5958(x+0.044715x^3)); |err| ~1e-3 << bf16 quant noise
__device__ __forceinline__ float gelu_f(float v) {
  float v3 = v * v * v;
  float y = 1.5957691216057308f * v + 0.0713548162726009f * v3;
  return v / (1.f + __expf(-y));
}

__device__ __forceinline__ void gload16(const void* g, void* l) {
  __builtin_amdgcn_global_load_lds((const __attribute__((address_space(1))) void*)g,
                                   (__attribute__((address_space(3))) void*)l, 16, 0, 0);
}

// shifted-window mapping: windowed token (b_, n) -> original row index in x
__device__ __forceinline__ int win2orig(int b_, int n) {
  int b = b_ >> 6, wi = b_ & 63;
  int hs = (wi >> 3) * 8 + (n >> 3);
  int ws = (wi & 7) * 8 + (n & 7);
  int hq = (hs + SHIFT_) & 63;
  int wq = (ws + SHIFT_) & 63;
  return b * LL + hq * WWID + wq;
}

// ---------------- tiny setup kernels ----------------
__global__ void cvt_k(const float* __restrict__ s, u16* __restrict__ d, int n) {
  int i = blockIdx.x * 256 + threadIdx.x;
  if (i < n) d[i] = f2bf(s[i]);
}

__global__ void cpb_k(const float* __restrict__ ct, const float* __restrict__ w1,
                      const float* __restrict__ b1, const float* __restrict__ w2,
                      float* __restrict__ t2) {
  int t = blockIdx.x * 256 + threadIdx.x;
  if (t >= 225 * 16) return;
  int rr = t >> 4, h = t & 15;
  float c0 = ct[rr * 2], c1 = ct[rr * 2 + 1];
  float acc = 0.f;
  for (int j = 0; j < 512; j++) {
    float hv = fmaxf(w1[j * 2] * c0 + w1[j * 2 + 1] * c1 + b1[j], 0.f);
    acc += hv * w2[h * 512 + j];
  }
  t2[t] = acc;
}

__global__ void bias_k(const float* __restrict__ t2, const int* __restrict__ rpi,
                       float* __restrict__ b16) {
  int t = blockIdx.x * 256 + threadIdx.x;   // h*4096 + n*64 + m
  int nm = t & 4095;
  int h = t >> 12;
  float v = t2[rpi[nm] * 16 + h];
  b16[t] = 16.0f / (1.0f + __expf(-v));
}

__global__ void scale_k(const float* __restrict__ ls, float* __restrict__ sc) {
  int t = threadIdx.x;
  if (t < HEADS) sc[t] = __expf(fminf(ls[t], 4.6051701859880914f)); // ln(100)
}

// x (fp32) -> xw (bf16) in shifted-window token order [b_*64+n][512]
__global__ __launch_bounds__(256) void xw_k(const float* __restrict__ x, u16* __restrict__ xw) {
  int t = blockIdx.x * 256 + threadIdx.x;
  int row = t >> 6;
  int col = (t & 63) * 8;
  const float* src = x + (size_t)win2orig(row >> 6, row & 63) * CCH + col;
  float4 a = *(const float4*)src;
  float4 b = *(const float4*)(src + 4);
  uint4 o = make_uint4(cvtpk(a.x, a.y), cvtpk(a.z, a.w),
                       cvtpk(b.x, b.y), cvtpk(b.z, b.w));
  *(uint4*)(xw + (size_t)row * CCH + col) = o;
}

// ---------------- MFMA GEMM: 8-phase 256x256 tile, 16x16x32 MFMA ----------------
// A bf16 [M][K], B bf16 [N][K] -> C = A @ B^T.
// 8 waves (512 thr), wave grid 2M x 4N, wave tile 128x64, acc[8][4] f32x4.
// LDS 128KB: 2 dbuf x (A 256x64 (32KB) + B 256x64 (32KB)).
// K-loop: per K-tile (BK=64) 4 phases, each:
//   { ds_read subtile (8 or 4 b128) ; stage (phases 0-1 only) ; s_barrier ;
//     lgkmcnt(0)+sched_barrier ; setprio(1) ; 16 MFMA ; setprio(0) ; s_barrier }
// All 8 stage loads (tile it+1 -> other buffer) issue in phases 0-1 -> the
// per-K-tile vmcnt(0) before phase-3's end barrier has ~2.5 phases of slack.
// mfma(bf, af) (swapped): acc holds C^T; lane owns row m=base+(l&15), regs
// walk 4 consecutive cols n = base + (l>>4)*4 + r -> packed 8B stores,
// 4 lanes cover a 32B sector.
// LDS swizzle: 8 chunks of 16B per 128B row; chunk c stored at c^(row&7),
// applied on the per-lane GLOBAL source addr (LDS dest linear, m173 pattern).
// Read side: c' = (kh*4 + (l>>4)) ^ (l&7) -> 2-way bank aliasing max (free).
// XCD swizzle: lin%8 -> XCD, contiguous M-chunk per XCD for L2 reuse.
// MODE 0: QKV (+q/v bias, scatter to [b_][h][n][d] bf16)
// MODE 1: proj (+proj_b, bf16 scatter to original token order)
// MODE 2: fc1  (+fc1_b, fast GELU, bf16 ld=HIDN)
// MODE 3: fc2  (+fc2_b, bf16 ld=CCH)
template<int MODE, int NBN>
__global__ __launch_bounds__(512, 2) void gemm256_k(
    const u16* __restrict__ A, const u16* __restrict__ Bw,
    const float* __restrict__ bias,
    const float* __restrict__ qbias, const float* __restrict__ vbias,
    u16* __restrict__ o0, u16* __restrict__ o1, u16* __restrict__ o2,
    int K, int mchunk)
{
  // [buf0: A 16384 u16 | B 16384 u16][buf1: ...] = 128KB
  __shared__ __align__(16) u16 smem[2 * 32768];
  const int t = threadIdx.x;
  const int lin = blockIdx.x;
  const int xcd = lin & 7;
  const int j = lin >> 3;
  const int m0 = (xcd * mchunk + j / NBN) * 256;
  const int n0 = (j % NBN) * 256;
  const int lane = t & 63;
  const int wv = t >> 6;          // 0..7
  const int wr = wv >> 2;         // 0..1  (M half)
  const int wc = wv & 3;          // 0..3  (N quarter)
  const int l15 = lane & 15;
  const int l4 = lane >> 4;       // 0..3

  // staging per-thread constants: row-in-half rl, swizzled k-chunk cg
  const int rl = t >> 3;                       // 0..63
  const int cg = (t & 7) ^ ((t >> 3) & 7);     // global chunk for lds slot t&7
  // read-side swizzled chunks (row&7 == l&7 for all frag rows)
  const int ck0 = (l4) ^ (lane & 7);           // kh=0
  const int ck1 = (4 + l4) ^ (lane & 7);       // kh=1

  // stage unit u: 0=A-half0, 1=A-half1, 2=B-half0, 3=B-half1 (16KB = 2 loads)
  auto stageU = [&](int T, int u, int bi) {
    const u16* mat = (u < 2) ? A : Bw;
    const int gbase = ((u < 2) ? m0 : n0) + (u & 1) * 128;
    size_t roff = (size_t)(gbase + rl) * K + (size_t)T * 64 + cg * 8;
    char* lds = (char*)smem + bi * 65536 + (u >= 2 ? 32768 : 0) + (u & 1) * 16384 + wv * 1024;
    gload16(mat + roff, lds);
    gload16(mat + roff + (size_t)64 * K, lds + 8192);
  };

  f32x4 acc[8][4] = {};

  const int NT = K >> 6;
  // prologue: stage tile 0 into buf 0
  #pragma unroll
  for (int u = 0; u < 4; u++) stageU(0, u, 0);
  asm volatile("s_waitcnt vmcnt(0)" ::: "memory");
  __builtin_amdgcn_s_barrier();

  for (int it = 0; it < NT; ++it) {
    const int cur = it & 1, nxt = cur ^ 1;
    const u16* bufA = smem + cur * 32768;
    const u16* bufB = bufA + 16384;
    const bool st = (it + 1 < NT);
    bf16x8 bfr[4];

    // ---- phase 0: (mh=0, kh=0); stage A0,A1(it+1)
    {
      bf16x8 afr[4];
      #pragma unroll
      for (int nf = 0; nf < 4; nf++)
        bfr[nf] = *(const bf16x8*)&bufB[(wc * 64 + nf * 16 + l15) * 64 + ck0 * 8];
      #pragma unroll
      for (int fm = 0; fm < 4; fm++)
        afr[fm] = *(const bf16x8*)&bufA[(wr * 128 + fm * 16 + l15) * 64 + ck0 * 8];
      if (st) { stageU(it + 1, 0, nxt); stageU(it + 1, 1, nxt); }
      __builtin_amdgcn_s_barrier();
      asm volatile("s_waitcnt lgkmcnt(0)" ::: "memory");
      __builtin_amdgcn_sched_barrier(0);
      __builtin_amdgcn_s_setprio(1);
      #pragma unroll
      for (int fm = 0; fm < 4; fm++)
        #pragma unroll
        for (int nf = 0; nf < 4; nf++)
          acc[fm][nf] = __builtin_amdgcn_mfma_f32_16x16x32_bf16(bfr[nf], afr[fm], acc[fm][nf], 0, 0, 0);
      __builtin_amdgcn_s_setprio(0);
      __builtin_amdgcn_s_barrier();
    }
    // ---- phase 1: (mh=1, kh=0); stage B0,B1(it+1)
    {
      bf16x8 afr[4];
      #pragma unroll
      for (int fm = 0; fm < 4; fm++)
        afr[fm] = *(const bf16x8*)&bufA[(wr * 128 + 64 + fm * 16 + l15) * 64 + ck0 * 8];
      if (st) { stageU(it + 1, 2, nxt); stageU(it + 1, 3, nxt); }
      __builtin_amdgcn_s_barrier();
      asm volatile("s_waitcnt lgkmcnt(0)" ::: "memory");
      __builtin_amdgcn_sched_barrier(0);
      __builtin_amdgcn_s_setprio(1);
      #pragma unroll
      for (int fm = 0; fm < 4; fm++)
        #pragma unroll
        for (int nf = 0; nf < 4; nf++)
          acc[4 + fm][nf] = __builtin_amdgcn_mfma_f32_16x16x32_bf16(bfr[nf], afr[fm], acc[4 + fm][nf], 0, 0, 0);
      __builtin_amdgcn_s_setprio(0);
      __builtin_amdgcn_s_barrier();
    }
    // ---- phase 2: (mh=0, kh=1)
    {
      bf16x8 afr[4];
      #pragma unroll
      for (int nf = 0; nf < 4; nf++)
        bfr[nf] = *(const bf16x8*)&bufB[(wc * 64 + nf * 16 + l15) * 64 + ck1 * 8];
      #pragma unroll
      for (int fm = 0; fm < 4; fm++)
        afr[fm] = *(const bf16x8*)&bufA[(wr * 128 + fm * 16 + l15) * 64 + ck1 * 8];
      __builtin_amdgcn_s_barrier();
      asm volatile("s_waitcnt lgkmcnt(0)" ::: "memory");
      __builtin_amdgcn_sched_barrier(0);
      __builtin_amdgcn_s_setprio(1);
      #pragma unroll
      for (int fm = 0; fm < 4; fm++)
        #pragma unroll
        for (int nf = 0; nf < 4; nf++)
          acc[fm][nf] = __builtin_amdgcn_mfma_f32_16x16x32_bf16(bfr[nf], afr[fm], acc[fm][nf], 0, 0, 0);
      __builtin_amdgcn_s_setprio(0);
      __builtin_amdgcn_s_barrier();
    }
    // ---- phase 3: (mh=1, kh=1); vmcnt(0) (stages fully issued 2.5 phases ago)
    {
      bf16x8 afr[4];
      #pragma unroll
      for (int fm = 0; fm < 4; fm++)
        afr[fm] = *(const bf16x8*)&bufA[(wr * 128 + 64 + fm * 16 + l15) * 64 + ck1 * 8];
      __builtin_amdgcn_s_barrier();
      asm volatile("s_waitcnt lgkmcnt(0)" ::: "memory");
      __builtin_amdgcn_sched_barrier(0);
      __builtin_amdgcn_s_setprio(1);
      #pragma unroll
      for (int fm = 0; fm < 4; fm++)
        #pragma unroll
        for (int nf = 0; nf < 4; nf++)
          acc[4 + fm][nf] = __builtin_amdgcn_mfma_f32_16x16x32_bf16(bfr[nf], afr[fm], acc[4 + fm][nf], 0, 0, 0);
      __builtin_amdgcn_s_setprio(0);
      asm volatile("s_waitcnt vmcnt(0)" ::: "memory");
      __builtin_amdgcn_s_barrier();
    }
  }

  // epilogue: acc holds C^T. lane: m = m0+wr*128+mf*16+(l&15) fixed,
  // n = n0+wc*64+nf*16+(l>>4)*4 + {0..3} -> 8B packed stores, sector-complete.
  const int part = n0 >> 9;   // MODE 0 only (256-tile never spans q/k/v parts)
  u16* qkvdst = (MODE == 0) ? (part == 0 ? o0 : (part == 1 ? o1 : o2)) : o0;
  const int l4q = l4 * 4;
  #pragma unroll
  for (int mf = 0; mf < 8; mf++) {
    const int grow = m0 + wr * 128 + mf * 16 + l15;
    size_t rowbase;
    if (MODE == 0) {
      int b_ = grow >> 6, n = grow & 63;
      rowbase = ((size_t)b_ * HEADS) * (NTOK * DDIM) + (size_t)n * DDIM;
    } else if (MODE == 1) {
      rowbase = (size_t)win2orig(grow >> 6, grow & 63) * CCH;
    } else if (MODE == 2) {
      rowbase = (size_t)grow * HIDN;
    } else {
      rowbase = (size_t)grow * CCH;
    }
    #pragma unroll
    for (int nf = 0; nf < 4; nf++) {
      const int n = n0 + wc * 64 + nf * 16 + l4q;   // 4-aligned
      float v0 = acc[mf][nf][0];
      float v1 = acc[mf][nf][1];
      float v2 = acc[mf][nf][2];
      float v3 = acc[mf][nf][3];
      if (MODE == 0) {
        const int cc = n & 511;
        if (part == 0) {
          float4 b4 = *(const float4*)(qbias + cc);
          v0 += b4.x; v1 += b4.y; v2 += b4.z; v3 += b4.w;
        } else if (part == 2) {
          float4 b4 = *(const float4*)(vbias + cc);
          v0 += b4.x; v1 += b4.y; v2 += b4.z; v3 += b4.w;
        }
      } else {
        float4 b4 = *(const float4*)(bias + n);
        v0 += b4.x; v1 += b4.y; v2 += b4.z; v3 += b4.w;
        if (MODE == 2) {
          v0 = gelu_f(v0); v1 = gelu_f(v1); v2 = gelu_f(v2); v3 = gelu_f(v3);
        }
      }
      uint2 pk = make_uint2(cvtpk(v0, v1), cvtpk(v2, v3));
      if (MODE == 0) {
        const int cc = n & 511;
        const int hh = cc >> 5, dd = cc & 31;
        *(uint2*)(qkvdst + rowbase + (size_t)hh * (NTOK * DDIM) + dd) = pk;
      } else {
        *(uint2*)(o0 + rowbase + n) = pk;
      }
    }
  }
}

// ---------------- attention: one wave per (window, head), in-register softmax ----------------
__global__ __launch_bounds__(64) void attn_k(
    const u16* __restrict__ qb, const u16* __restrict__ kb, const u16* __restrict__ vb,
    const float* __restrict__ bias16, const float* __restrict__ scale,
    const float* __restrict__ amask, u16* __restrict__ attn_out)
{
  __shared__ u16 Pmat[64][72];   // bf16 P (unnormalized), 144B rows (16B-aligned)
  __shared__ u16 vT[32][72];     // V transposed [d][tok]

  int bh = blockIdx.x;
  int b_ = bh >> 4, h = bh & 15;
  int wi = b_ & 63;
  int lane = threadIdx.x;
  int l15 = lane & 15, quad = lane >> 4;
  const u16* qs = qb + (size_t)bh * (NTOK * DDIM);
  const u16* ks = kb + (size_t)bh * (NTOK * DDIM);
  const u16* vs = vb + (size_t)bh * (NTOK * DDIM);

  bf16x8 qf[4], kf[4];
  #pragma unroll
  for (int mt = 0; mt < 4; mt++) {
    qf[mt] = *(const bf16x8*)(qs + (mt * 16 + l15) * DDIM + quad * 8);
    kf[mt] = *(const bf16x8*)(ks + (mt * 16 + l15) * DDIM + quad * 8);
  }
  // fused cosine normalization: lanes {l15, +16, +32, +48} share a row
  #pragma unroll
  for (int mt = 0; mt < 4; mt++) {
    float sq = 0.f, sk = 0.f;
    #pragma unroll
    for (int jj = 0; jj < 8; jj++) {
      float a = bf2f((u16)qf[mt][jj]); sq += a * a;
      float b = bf2f((u16)kf[mt][jj]); sk += b * b;
    }
    sq += __shfl_xor(sq, 16); sq += __shfl_xor(sq, 32);
    sk += __shfl_xor(sk, 16); sk += __shfl_xor(sk, 32);
    float iq = 1.f / fmaxf(sqrtf(sq), 1e-12f);
    float ik = 1.f / fmaxf(sqrtf(sk), 1e-12f);
    #pragma unroll
    for (int jj = 0; jj < 8; jj++) {
      qf[mt][jj] = (short)f2bf(bf2f((u16)qf[mt][jj]) * iq);
      kf[mt][jj] = (short)f2bf(bf2f((u16)kf[mt][jj]) * ik);
    }
  }
  // S = qn @ kn^T (in registers)
  f32x4 s[4][4];
  #pragma unroll
  for (int mt = 0; mt < 4; mt++)
    #pragma unroll
    for (int nt = 0; nt < 4; nt++) {
      f32x4 c = {0.f, 0.f, 0.f, 0.f};
      s[mt][nt] = __builtin_amdgcn_mfma_f32_16x16x32_bf16(qf[mt], kf[nt], c, 0, 0, 0);
    }
  // stage V^T
  #pragma unroll
  for (int d8 = 0; d8 < 4; d8++) {
    bf16x8 vv = *(const bf16x8*)(vs + lane * DDIM + d8 * 8);
    #pragma unroll
    for (int jj = 0; jj < 8; jj++) vT[d8 * 8 + jj][lane] = (u16)vv[jj];
  }

  // in-register softmax: row = mt*16+quad*4+i (16 lanes/row across l15)
  float sc = scale[h];
  float rinv[4][4];
  const float* bbase = bias16 + (size_t)h * 4096;
  const float* mbase = amask + (size_t)wi * 4096;
  #pragma unroll
  for (int mt = 0; mt < 4; mt++) {
    #pragma unroll
    for (int i = 0; i < 4; i++) {
      int row = mt * 16 + quad * 4 + i;
      const float* bro = bbase + row * 64;
      const float* mro = mbase + row * 64;
      float p[4];
      float mx = -1e30f;
      #pragma unroll
      for (int nt = 0; nt < 4; nt++) {
        int col = nt * 16 + l15;
        float vv = s[mt][nt][i] * sc + bro[col] + mro[col];
        p[nt] = vv;
        mx = fmaxf(mx, vv);
      }
      mx = fmaxf(mx, __shfl_xor(mx, 1));
      mx = fmaxf(mx, __shfl_xor(mx, 2));
      mx = fmaxf(mx, __shfl_xor(mx, 4));
      mx = fmaxf(mx, __shfl_xor(mx, 8));
      float sum = 0.f;
      #pragma unroll
      for (int nt = 0; nt < 4; nt++) {
        float e = __expf(p[nt] - mx);
        p[nt] = e;
        sum += e;
      }
      sum += __shfl_xor(sum, 1);
      sum += __shfl_xor(sum, 2);
      sum += __shfl_xor(sum, 4);
      sum += __shfl_xor(sum, 8);
      rinv[mt][i] = 1.f / sum;
      #pragma unroll
      for (int nt = 0; nt < 4; nt++)
        Pmat[row][nt * 16 + l15] = f2bf(p[nt]);
    }
  }
  __syncthreads();

  // O = P @ V (1/sum folded into epilogue)
  f32x4 oacc[4][2] = {};
  #pragma unroll
  for (int ks2 = 0; ks2 < 2; ks2++) {
    bf16x8 pf[4], vf[2];
    #pragma unroll
    for (int mt = 0; mt < 4; mt++)
      pf[mt] = *(const bf16x8*)&Pmat[mt * 16 + l15][ks2 * 32 + quad * 8];
    #pragma unroll
    for (int nt = 0; nt < 2; nt++)
      vf[nt] = *(const bf16x8*)&vT[nt * 16 + l15][ks2 * 32 + quad * 8];
    #pragma unroll
    for (int mt = 0; mt < 4; mt++)
      #pragma unroll
      for (int nt = 0; nt < 2; nt++)
        oacc[mt][nt] = __builtin_amdgcn_mfma_f32_16x16x32_bf16(pf[mt], vf[nt], oacc[mt][nt], 0, 0, 0);
  }
  #pragma unroll
  for (int mt = 0; mt < 4; mt++)
    #pragma unroll
    for (int nt = 0; nt < 2; nt++)
      #pragma unroll
      for (int i = 0; i < 4; i++) {
        int n = mt * 16 + quad * 4 + i;
        int d = nt * 16 + l15;
        float val = oacc[mt][nt][i] * rinv[mt][i];
        attn_out[(size_t)(b_ * 64 + n) * CCH + h * DDIM + d] = f2bf(val);
      }
}

// ---------------- LayerNorm + residual kernels (one wave per row) ----------------
__global__ __launch_bounds__(256) void ln_res_k(
    const float* __restrict__ xin, const u16* __restrict__ pin,
    const float* __restrict__ gam, const float* __restrict__ bet,
    float* __restrict__ x1f, u16* __restrict__ x1b)
{
  int row = blockIdx.x * 4 + (threadIdx.x >> 6);
  int lane = threadIdx.x & 63;
  size_t base = (size_t)row * CCH + lane * 8;
  uint4 u = *(const uint4*)(pin + base);
  unsigned w[4] = {u.x, u.y, u.z, u.w};
  float pv[8];
  #pragma unroll
  for (int j = 0; j < 4; j++) {
    pv[j * 2] = bf2f(w[j] & 0xffffu);
    pv[j * 2 + 1] = bf2f(w[j] >> 16);
  }
  float4 x0 = *(const float4*)(xin + base);
  float4 x1 = *(const float4*)(xin + base + 4);
  float xr[8] = {x0.x, x0.y, x0.z, x0.w, x1.x, x1.y, x1.z, x1.w};
  float s = 0.f, sq = 0.f;
  #pragma unroll
  for (int j = 0; j < 8; j++) { s += pv[j]; sq += pv[j] * pv[j]; }
  #pragma unroll
  for (int o = 32; o > 0; o >>= 1) { s += __shfl_xor(s, o, 64); sq += __shfl_xor(sq, o, 64); }
  float mean = s * (1.0f / 512.0f);
  float var = sq * (1.0f / 512.0f) - mean * mean;
  float rstd = rsqrtf(var + 1e-5f);
  float4 g0 = *(const float4*)(gam + lane * 8);
  float4 g1 = *(const float4*)(gam + lane * 8 + 4);
  float4 b0 = *(const float4*)(bet + lane * 8);
  float4 b1 = *(const float4*)(bet + lane * 8 + 4);
  float gg[8] = {g0.x, g0.y, g0.z, g0.w, g1.x, g1.y, g1.z, g1.w};
  float bb[8] = {b0.x, b0.y, b0.z, b0.w, b1.x, b1.y, b1.z, b1.w};
  float val[8];
  #pragma unroll
  for (int j = 0; j < 8; j++)
    val[j] = xr[j] + (pv[j] - mean) * rstd * gg[j] + bb[j];
  *(float4*)(x1f + base)     = make_float4(val[0], val[1], val[2], val[3]);
  *(float4*)(x1f + base + 4) = make_float4(val[4], val[5], val[6], val[7]);
  *(uint4*)(x1b + base) = make_uint4(cvtpk(val[0], val[1]), cvtpk(val[2], val[3]),
                                     cvtpk(val[4], val[5]), cvtpk(val[6], val[7]));
}

__global__ __launch_bounds__(256) void ln_fin_k(
    const u16* __restrict__ mlp, const float* __restrict__ gam,
    const float* __restrict__ bet, float* __restrict__ io)
{
  int row = blockIdx.x * 4 + (threadIdx.x >> 6);
  int lane = threadIdx.x & 63;
  size_t base = (size_t)row * CCH + lane * 8;
  uint4 u = *(const uint4*)(mlp + base);
  unsigned w[4] = {u.x, u.y, u.z, u.w};
  float pv[8];
  #pragma unroll
  for (int j = 0; j < 4; j++) {
    pv[j * 2] = bf2f(w[j] & 0xffffu);
    pv[j * 2 + 1] = bf2f(w[j] >> 16);
  }
  float s = 0.f, sq = 0.f;
  #pragma unroll
  for (int j = 0; j < 8; j++) { s += pv[j]; sq += pv[j] * pv[j]; }
  #pragma unroll
  for (int o = 32; o > 0; o >>= 1) { s += __shfl_xor(s, o, 64); sq += __shfl_xor(sq, o, 64); }
  float mean = s * (1.0f / 512.0f);
  float var = sq * (1.0f / 512.0f) - mean * mean;
  float rstd = rsqrtf(var + 1e-5f);
  float4 g0 = *(const float4*)(gam + lane * 8);
  float4 g1 = *(const float4*)(gam + lane * 8 + 4);
  float4 b0 = *(const float4*)(bet + lane * 8);
  float4 b1 = *(const float4*)(bet + lane * 8 + 4);
  float gg[8] = {g0.x, g0.y, g0.z, g0.w, g1.x, g1.y, g1.z, g1.w};
  float bb[8] = {b0.x, b0.y, b0.z, b0.w, b1.x, b1.y, b1.z, b1.w};
  float4 i0 = *(const float4*)(io + base);
  float4 i1 = *(const float4*)(io + base + 4);
  float iv[8] = {i0.x, i0.y, i0.z, i0.w, i1.x, i1.y, i1.z, i1.w};
  float out[8];
  #pragma unroll
  for (int j = 0; j < 8; j++)
    out[j] = iv[j] + (pv[j] - mean) * rstd * gg[j] + bb[j];
  *(float4*)(io + base)     = make_float4(out[0], out[1], out[2], out[3]);
  *(float4*)(io + base + 4) = make_float4(out[4], out[5], out[6], out[7]);
}

// ---------------- launcher ----------------
#define OFF_Q     ((size_t)0)
#define OFF_K     ((size_t)67108864)
#define OFF_V     ((size_t)134217728)
#define OFF_ATTN  ((size_t)201326592)
#define OFF_X1B   ((size_t)268435456)
#define OFF_WQKV  ((size_t)335544320)
#define OFF_WPROJ ((size_t)337117184)
#define OFF_WFC1  ((size_t)337641472)
#define OFF_WFC2  ((size_t)339738624)
#define OFF_T2    ((size_t)341835776)
#define OFF_B16   ((size_t)341852160)
#define OFF_SC    ((size_t)342114304)

extern "C" void kernel_launch(void* const* d_in, const int* in_sizes, int n_in,
                              void* d_out, int out_size, void* d_ws, size_t ws_size,
                              hipStream_t stream) {
  const float* x        = (const float*)d_in[0];
  const float* qkv_w    = (const float*)d_in[1];
  const float* q_bias   = (const float*)d_in[2];
  const float* v_bias   = (const float*)d_in[3];
  const float* lscale   = (const float*)d_in[4];
  const float* cpb_w1   = (const float*)d_in[5];
  const float* cpb_b1   = (const float*)d_in[6];
  const float* cpb_w2   = (const float*)d_in[7];
  const float* proj_w   = (const float*)d_in[8];
  const float* proj_b   = (const float*)d_in[9];
  const float* n1g      = (const float*)d_in[10];
  const float* n1b      = (const float*)d_in[11];
  const float* n2g      = (const float*)d_in[12];
  const float* n2b      = (const float*)d_in[13];
  const float* fc1_w    = (const float*)d_in[14];
  const float* fc1_b    = (const float*)d_in[15];
  const float* fc2_w    = (const float*)d_in[16];
  const float* fc2_b    = (const float*)d_in[17];
  const float* ctab     = (const float*)d_in[18];
  const float* amask    = (const float*)d_in[19];
  const int*   rpi      = (const int*)d_in[20];

  char* ws = (char*)d_ws;
  float* outp = (float*)d_out;

  u16*   q_buf    = (u16*)(ws + OFF_Q);
  u16*   k_buf    = (u16*)(ws + OFF_K);
  u16*   v_buf    = (u16*)(ws + OFF_V);
  u16*   proj_out = (u16*)(ws + OFF_Q);     // reuse R0 (bf16 now)
  u16*   hid      = (u16*)(ws + OFF_Q);     // reuse R0 (half-batch)
  u16*   xw       = (u16*)(ws + OFF_ATTN);  // R1 (dead after QKV gemm)
  u16*   attn_out = (u16*)(ws + OFF_ATTN);
  u16*   mlp_out  = (u16*)(ws + OFF_ATTN);
  u16*   x1b      = (u16*)(ws + OFF_X1B);
  u16*   wqkv     = (u16*)(ws + OFF_WQKV);
  u16*   wproj    = (u16*)(ws + OFF_WPROJ);
  u16*   wfc1     = (u16*)(ws + OFF_WFC1);
  u16*   wfc2     = (u16*)(ws + OFF_WFC2);
  float* t2       = (float*)(ws + OFF_T2);
  float* b16      = (float*)(ws + OFF_B16);
  float* scbuf    = (float*)(ws + OFF_SC);

  cvt_k<<<(1536 * 512 + 255) / 256, 256, 0, stream>>>(qkv_w, wqkv, 1536 * 512);
  cvt_k<<<(512 * 512 + 255) / 256, 256, 0, stream>>>(proj_w, wproj, 512 * 512);
  cvt_k<<<(2048 * 512 + 255) / 256, 256, 0, stream>>>(fc1_w, wfc1, 2048 * 512);
  cvt_k<<<(512 * 2048 + 255) / 256, 256, 0, stream>>>(fc2_w, wfc2, 512 * 2048);
  cpb_k<<<15, 256, 0, stream>>>(ctab, cpb_w1, cpb_b1, cpb_w2, t2);
  bias_k<<<256, 256, 0, stream>>>(t2, rpi, b16);
  scale_k<<<1, 64, 0, stream>>>(lscale, scbuf);

  // x -> xw (bf16, shifted-window order)
  xw_k<<<MTOT * 64 / 256, 256, 0, stream>>>(x, xw);
  // QKV: M=65536 (256 m-tiles, mchunk 32), N=1536 (6 n-tiles)
  gemm256_k<0, 6><<<256 * 6, 512, 0, stream>>>(
      xw, wqkv, nullptr, q_bias, v_bias, q_buf, k_buf, v_buf, 512, 32);
  // attention (fused cosine norm, in-register softmax)
  attn_k<<<BWIN * HEADS, 64, 0, stream>>>(q_buf, k_buf, v_buf, b16, scbuf, amask, attn_out);
  // proj: N=512 (2 n-tiles), bf16 out, window-reverse fused
  gemm256_k<1, 2><<<256 * 2, 512, 0, stream>>>(
      attn_out, wproj, proj_b, nullptr, nullptr, proj_out, nullptr, nullptr, 512, 32);
  // x1 = x + LN1(proj_out)
  ln_res_k<<<MTOT / 4, 256, 0, stream>>>(x, proj_out, n1g, n1b, outp, x1b);
  // MLP in two row-halves (M=32768 -> 128 m-tiles, mchunk 16)
  for (int half = 0; half < 2; half++) {
    const u16* a1 = x1b + (size_t)half * (MTOT / 2) * CCH;
    u16* m1 = mlp_out + (size_t)half * (MTOT / 2) * CCH;
    gemm256_k<2, 8><<<128 * 8, 512, 0, stream>>>(
        a1, wfc1, fc1_b, nullptr, nullptr, hid, nullptr, nullptr, 512, 16);
    gemm256_k<3, 2><<<128 * 2, 512, 0, stream>>>(
        hid, wfc2, fc2_b, nullptr, nullptr, m1, nullptr, nullptr, 2048, 16);
  }
  // out = x1 + LN2(mlp)
  ln_fin_k<<<MTOT / 4, 256, 0, stream>>>(mlp_out, n2g, n2b, outp);
}